// Round 3
// baseline (105.279 us; speedup 1.0000x reference)
//
#include <hip/hip_runtime.h>

#define NUM_CLASSES 256
#define CLAMP_MIN_F (-10.0f)

typedef float v4f __attribute__((ext_vector_type(4)));  // native vector: ok for nontemporal builtin

// One wave (64 lanes) per row; lane l covers cols 4l..4l+3 via one 16B load.
// 4 rows per wave-iteration for MLP; targets via scalar (readfirstlane) load;
// logits via nontemporal loads (streamed once, don't pollute L2/L3).
// fp32 per-row partial -> double accumulator -> deterministic block partials.

__device__ __forceinline__ float row_partial(const v4f v4, const int j0, const int t) {
    const bool t_not_last = (t < NUM_CLASSES - 1);
    float s = 0.0f;
    #pragma unroll
    for (int e = 0; e < 4; ++e) {
        const int j   = j0 + e;
        const float v = v4[e];
        const float c1 = fmaxf(v,  CLAMP_MIN_F);   // term1: j <  t
        const float c2 = fmaxf(-v, CLAMP_MIN_F);   // term2: j >= t (t != K-1)
        s += (j < t) ? c1 : (t_not_last ? c2 : 0.0f);
    }
    return s;
}

__global__ __launch_bounds__(256) void ordloss_main(
    const float* __restrict__ logits,
    const int* __restrict__ targets,
    double* __restrict__ partials,
    int batch)
{
    const int lane          = threadIdx.x & 63;
    const int wave_in_block = threadIdx.x >> 6;
    const int waves_per_blk = blockDim.x >> 6;
    const int global_wave   = blockIdx.x * waves_per_blk + wave_in_block;
    const int total_waves   = gridDim.x * waves_per_blk;
    const int j0            = lane * 4;

    double acc = 0.0;

    int row = global_wave;
    // unrolled-by-4 grid-stride: 4 independent 16B loads in flight per wave
    for (; row + 3 * total_waves < batch; row += 4 * total_waves) {
        const int r0 = row;
        const int r1 = row + total_waves;
        const int r2 = row + 2 * total_waves;
        const int r3 = row + 3 * total_waves;

        // wave-uniform scalar loads of targets
        const int t0 = targets[__builtin_amdgcn_readfirstlane(r0)];
        const int t1 = targets[__builtin_amdgcn_readfirstlane(r1)];
        const int t2 = targets[__builtin_amdgcn_readfirstlane(r2)];
        const int t3 = targets[__builtin_amdgcn_readfirstlane(r3)];

        const v4f* p0 = reinterpret_cast<const v4f*>(logits + (size_t)r0 * NUM_CLASSES) + lane;
        const v4f* p1 = reinterpret_cast<const v4f*>(logits + (size_t)r1 * NUM_CLASSES) + lane;
        const v4f* p2 = reinterpret_cast<const v4f*>(logits + (size_t)r2 * NUM_CLASSES) + lane;
        const v4f* p3 = reinterpret_cast<const v4f*>(logits + (size_t)r3 * NUM_CLASSES) + lane;

        const v4f v0 = __builtin_nontemporal_load(p0);
        const v4f v1 = __builtin_nontemporal_load(p1);
        const v4f v2 = __builtin_nontemporal_load(p2);
        const v4f v3 = __builtin_nontemporal_load(p3);

        acc += (double)row_partial(v0, j0, t0);
        acc += (double)row_partial(v1, j0, t1);
        acc += (double)row_partial(v2, j0, t2);
        acc += (double)row_partial(v3, j0, t3);
    }
    for (; row < batch; row += total_waves) {   // tail (unused: batch % (4*waves) == 0)
        const int t = targets[__builtin_amdgcn_readfirstlane(row)];
        const v4f v = __builtin_nontemporal_load(
            reinterpret_cast<const v4f*>(logits + (size_t)row * NUM_CLASSES) + lane);
        acc += (double)row_partial(v, j0, t);
    }

    // wave reduction (64 lanes) in double
    #pragma unroll
    for (int off = 32; off > 0; off >>= 1)
        acc += __shfl_down(acc, off, 64);

    __shared__ double lds[8];
    if (lane == 0) lds[wave_in_block] = acc;
    __syncthreads();

    if (threadIdx.x == 0) {
        double b = 0.0;
        for (int w = 0; w < waves_per_blk; ++w) b += lds[w];
        partials[blockIdx.x] = b;
    }
}

__global__ __launch_bounds__(256) void ordloss_final(
    const double* __restrict__ partials, int nparts,
    float* __restrict__ out, double inv_batch)
{
    __shared__ double lds[256];
    double a = 0.0;
    for (int i = threadIdx.x; i < nparts; i += 256) a += partials[i];
    lds[threadIdx.x] = a;
    __syncthreads();
    for (int s = 128; s > 0; s >>= 1) {
        if (threadIdx.x < s) lds[threadIdx.x] += lds[threadIdx.x + s];
        __syncthreads();
    }
    if (threadIdx.x == 0) out[0] = (float)(lds[0] * inv_batch);
}

extern "C" void kernel_launch(void* const* d_in, const int* in_sizes, int n_in,
                              void* d_out, int out_size, void* d_ws, size_t ws_size,
                              hipStream_t stream) {
    const float* logits  = (const float*)d_in[0];
    const int*   targets = (const int*)d_in[1];
    float*       out     = (float*)d_out;
    const int    batch   = in_sizes[1];   // 524288 rows

    double* partials = (double*)d_ws;     // 2048 doubles = 16 KB << ws_size
    const int nblocks = 2048;             // 8 blocks/CU x 4 waves = full residency

    ordloss_main<<<nblocks, 256, 0, stream>>>(logits, targets, partials, batch);
    ordloss_final<<<1, 256, 0, stream>>>(partials, nblocks, out, 1.0 / (double)batch);
}

// Round 4
// 98.342 us; speedup vs baseline: 1.0705x; 1.0705x over previous
//
#include <hip/hip_runtime.h>

#define NUM_CLASSES 256
#define CLAMP_MIN_F (-10.0f)

// One wave (64 lanes) per row; lane l covers cols 4l..4l+3 via one float4.
// Each wave processes 4 ADJACENT rows per iteration (4 KB contiguous per wave,
// grid collectively sweeps contiguous 32 MB chunks) -> 4 independent 16B loads
// in flight per wave without losing DRAM locality. Plain (cached) loads —
// nontemporal regressed in round 3.
// fp32 per-row partial -> double accumulator -> deterministic block partials.

__device__ __forceinline__ float row_partial(const float4 v4, const int j0, const int t) {
    const bool t_not_last = (t < NUM_CLASSES - 1);
    const float vv[4] = {v4.x, v4.y, v4.z, v4.w};
    float s = 0.0f;
    #pragma unroll
    for (int e = 0; e < 4; ++e) {
        const int j   = j0 + e;
        const float v = vv[e];
        const float c1 = fmaxf(v,  CLAMP_MIN_F);   // term1: j <  t
        const float c2 = fmaxf(-v, CLAMP_MIN_F);   // term2: j >= t (t != K-1)
        s += (j < t) ? c1 : (t_not_last ? c2 : 0.0f);
    }
    return s;
}

__global__ __launch_bounds__(256) void ordloss_main(
    const float* __restrict__ logits,
    const int* __restrict__ targets,
    double* __restrict__ partials,
    int batch)
{
    const int lane          = threadIdx.x & 63;
    const int wave_in_block = threadIdx.x >> 6;
    const int waves_per_blk = blockDim.x >> 6;
    const int global_wave   = blockIdx.x * waves_per_blk + wave_in_block;
    const int total_waves   = gridDim.x * waves_per_blk;
    const int j0            = lane * 4;

    double acc = 0.0;

    int row = global_wave * 4;
    const int stride = total_waves * 4;
    // 4 adjacent rows per wave-iteration: 4 independent contiguous 16B loads
    for (; row + 3 < batch; row += stride) {
        const int t0 = targets[row + 0];
        const int t1 = targets[row + 1];
        const int t2 = targets[row + 2];
        const int t3 = targets[row + 3];

        const float4* p = reinterpret_cast<const float4*>(
            logits + (size_t)row * NUM_CLASSES) + lane;
        const float4 v0 = p[0];
        const float4 v1 = p[64];
        const float4 v2 = p[128];
        const float4 v3 = p[192];

        acc += (double)row_partial(v0, j0, t0);
        acc += (double)row_partial(v1, j0, t1);
        acc += (double)row_partial(v2, j0, t2);
        acc += (double)row_partial(v3, j0, t3);
    }
    for (; row < batch; ++row) {   // tail (unused: batch % 4 == 0)
        const int t = targets[row];
        const float4 v = reinterpret_cast<const float4*>(
            logits + (size_t)row * NUM_CLASSES)[lane];
        acc += (double)row_partial(v, j0, t);
    }

    // wave reduction (64 lanes) in double
    #pragma unroll
    for (int off = 32; off > 0; off >>= 1)
        acc += __shfl_down(acc, off, 64);

    __shared__ double lds[8];
    if (lane == 0) lds[wave_in_block] = acc;
    __syncthreads();

    if (threadIdx.x == 0) {
        double b = 0.0;
        for (int w = 0; w < waves_per_blk; ++w) b += lds[w];
        partials[blockIdx.x] = b;
    }
}

__global__ __launch_bounds__(256) void ordloss_final(
    const double* __restrict__ partials, int nparts,
    float* __restrict__ out, double inv_batch)
{
    __shared__ double lds[256];
    double a = 0.0;
    for (int i = threadIdx.x; i < nparts; i += 256) a += partials[i];
    lds[threadIdx.x] = a;
    __syncthreads();
    for (int s = 128; s > 0; s >>= 1) {
        if (threadIdx.x < s) lds[threadIdx.x] += lds[threadIdx.x + s];
        __syncthreads();
    }
    if (threadIdx.x == 0) out[0] = (float)(lds[0] * inv_batch);
}

extern "C" void kernel_launch(void* const* d_in, const int* in_sizes, int n_in,
                              void* d_out, int out_size, void* d_ws, size_t ws_size,
                              hipStream_t stream) {
    const float* logits  = (const float*)d_in[0];
    const int*   targets = (const int*)d_in[1];
    float*       out     = (float*)d_out;
    const int    batch   = in_sizes[1];   // 524288 rows

    double* partials = (double*)d_ws;     // 2048 doubles = 16 KB << ws_size
    const int nblocks = 2048;             // 8 blocks/CU x 4 waves = full residency

    ordloss_main<<<nblocks, 256, 0, stream>>>(logits, targets, partials, batch);
    ordloss_final<<<1, 256, 0, stream>>>(partials, nblocks, out, 1.0 / (double)batch);
}

// Round 5
// 87.515 us; speedup vs baseline: 1.2030x; 1.1237x over previous
//
#include <hip/hip_runtime.h>

#define NUM_CLASSES 256
#define CLAMP_MIN_F (-10.0f)

typedef float v4f __attribute__((ext_vector_type(4)));  // native vector for nontemporal builtin

// One wave (64 lanes) per row; lane l covers cols 4l..4l+3 via one 16B load.
// Each wave processes 4 ADJACENT rows per iteration (4 KB contiguous per wave).
// Logits are read exactly once (512 MiB > L3) -> nontemporal loads mark lines
// evict-first, avoiding L2/L3 allocation thrash. Targets stay plain vector
// loads (round 3 showed the SMEM path + strided rows regress).
// fp32 per-row partial -> double accumulator -> deterministic block partials.

__device__ __forceinline__ float row_partial(const v4f v4, const int j0, const int t) {
    const bool t_not_last = (t < NUM_CLASSES - 1);
    float s = 0.0f;
    #pragma unroll
    for (int e = 0; e < 4; ++e) {
        const int j   = j0 + e;
        const float v = v4[e];
        const float c1 = fmaxf(v,  CLAMP_MIN_F);   // term1: j <  t
        const float c2 = fmaxf(-v, CLAMP_MIN_F);   // term2: j >= t (t != K-1)
        s += (j < t) ? c1 : (t_not_last ? c2 : 0.0f);
    }
    return s;
}

__global__ __launch_bounds__(256) void ordloss_main(
    const float* __restrict__ logits,
    const int* __restrict__ targets,
    double* __restrict__ partials,
    int batch)
{
    const int lane          = threadIdx.x & 63;
    const int wave_in_block = threadIdx.x >> 6;
    const int waves_per_blk = blockDim.x >> 6;
    const int global_wave   = blockIdx.x * waves_per_blk + wave_in_block;
    const int total_waves   = gridDim.x * waves_per_blk;
    const int j0            = lane * 4;

    double acc = 0.0;

    int row = global_wave * 4;
    const int stride = total_waves * 4;
    // 4 adjacent rows per wave-iteration: 4 independent contiguous 16B loads
    for (; row + 3 < batch; row += stride) {
        const int t0 = targets[row + 0];
        const int t1 = targets[row + 1];
        const int t2 = targets[row + 2];
        const int t3 = targets[row + 3];

        const v4f* p = reinterpret_cast<const v4f*>(
            logits + (size_t)row * NUM_CLASSES) + lane;
        const v4f v0 = __builtin_nontemporal_load(p);
        const v4f v1 = __builtin_nontemporal_load(p + 64);
        const v4f v2 = __builtin_nontemporal_load(p + 128);
        const v4f v3 = __builtin_nontemporal_load(p + 192);

        acc += (double)row_partial(v0, j0, t0);
        acc += (double)row_partial(v1, j0, t1);
        acc += (double)row_partial(v2, j0, t2);
        acc += (double)row_partial(v3, j0, t3);
    }
    for (; row < batch; ++row) {   // tail (unused: batch % 4 == 0)
        const int t = targets[row];
        const v4f v = __builtin_nontemporal_load(
            reinterpret_cast<const v4f*>(logits + (size_t)row * NUM_CLASSES) + lane);
        acc += (double)row_partial(v, j0, t);
    }

    // wave reduction (64 lanes) in double
    #pragma unroll
    for (int off = 32; off > 0; off >>= 1)
        acc += __shfl_down(acc, off, 64);

    __shared__ double lds[8];
    if (lane == 0) lds[wave_in_block] = acc;
    __syncthreads();

    if (threadIdx.x == 0) {
        double b = 0.0;
        for (int w = 0; w < waves_per_blk; ++w) b += lds[w];
        partials[blockIdx.x] = b;
    }
}

__global__ __launch_bounds__(256) void ordloss_final(
    const double* __restrict__ partials, int nparts,
    float* __restrict__ out, double inv_batch)
{
    __shared__ double lds[256];
    double a = 0.0;
    for (int i = threadIdx.x; i < nparts; i += 256) a += partials[i];
    lds[threadIdx.x] = a;
    __syncthreads();
    for (int s = 128; s > 0; s >>= 1) {
        if (threadIdx.x < s) lds[threadIdx.x] += lds[threadIdx.x + s];
        __syncthreads();
    }
    if (threadIdx.x == 0) out[0] = (float)(lds[0] * inv_batch);
}

extern "C" void kernel_launch(void* const* d_in, const int* in_sizes, int n_in,
                              void* d_out, int out_size, void* d_ws, size_t ws_size,
                              hipStream_t stream) {
    const float* logits  = (const float*)d_in[0];
    const int*   targets = (const int*)d_in[1];
    float*       out     = (float*)d_out;
    const int    batch   = in_sizes[1];   // 524288 rows

    double* partials = (double*)d_ws;     // 2048 doubles = 16 KB << ws_size
    const int nblocks = 2048;             // 8 blocks/CU x 4 waves = full residency

    ordloss_main<<<nblocks, 256, 0, stream>>>(logits, targets, partials, batch);
    ordloss_final<<<1, 256, 0, stream>>>(partials, nblocks, out, 1.0 / (double)batch);
}